// Round 1
// baseline (189.942 us; speedup 1.0000x reference)
//
#include <hip/hip_runtime.h>
#include <hip/hip_bf16.h>

// Kernel 1: per-row inclusive cumsum of durations.
// Derives B,S in-kernel: T = *T_ptr, B = BT/T, S = BS/B.
// Grid-strided over rows so host doesn't need B.
__global__ void lr_cumsum_kernel(const int* __restrict__ dur, int* __restrict__ cum,
                                 const int* __restrict__ T_ptr, int BS, int BT) {
    const int T = *T_ptr;
    const int B = BT / T;
    const int S = BS / B;
    __shared__ int sdata[1024];
    const int tid = threadIdx.x;
    for (int row = blockIdx.x; row < B; row += gridDim.x) {
        int carry = 0;
        for (int base = 0; base < S; base += 1024) {
            const int n = min(1024, S - base);
            __syncthreads();  // protect sdata reuse across chunks/rows
            int v = (tid < n) ? dur[row * S + base + tid] : 0;
            sdata[tid] = v;
            __syncthreads();
            // Hillis-Steele inclusive scan over 1024 slots
            #pragma unroll
            for (int off = 1; off < 1024; off <<= 1) {
                int add = (tid >= off) ? sdata[tid - off] : 0;
                __syncthreads();
                sdata[tid] += add;
                __syncthreads();
            }
            if (tid < n) cum[row * S + base + tid] = sdata[tid] + carry;
            carry += sdata[1023];  // chunk total (padded slots are 0)
        }
    }
}

// Kernel 2: one block per output frame (b,t). Binary search cum row for the
// source token, then vector-copy the H-vector (or zeros past the total).
__global__ __launch_bounds__(128)
void lr_expand_kernel(const float4* __restrict__ x, const int* __restrict__ cum,
                      float4* __restrict__ out, const int* __restrict__ T_ptr,
                      int BS, int BT, int H4) {
    const int T = *T_ptr;
    const int bt = blockIdx.x;
    const int b  = bt / T;
    const int t  = bt - b * T;
    const int B  = BT / T;
    const int S  = BS / B;

    // searchsorted(cum_row, t, side='right'): first j with cum[j] > t.
    const int* __restrict__ c = cum + b * S;
    int lo = 0, hi = S;
    while (lo < hi) {
        int mid = (lo + hi) >> 1;
        if (c[mid] <= t) lo = mid + 1; else hi = mid;
    }
    const bool valid = lo < S;
    const int idx = valid ? lo : (S - 1);

    const float4* __restrict__ src = x + (size_t)(b * S + idx) * H4;
    float4* __restrict__ dst = out + (size_t)bt * H4;
    const float4 zero = make_float4(0.f, 0.f, 0.f, 0.f);
    for (int i = threadIdx.x; i < H4; i += blockDim.x) {
        dst[i] = valid ? src[i] : zero;
    }
}

extern "C" void kernel_launch(void* const* d_in, const int* in_sizes, int n_in,
                              void* d_out, int out_size, void* d_ws, size_t ws_size,
                              hipStream_t stream) {
    const float* x     = (const float*)d_in[0];
    const int*   dur   = (const int*)d_in[1];
    const int*   T_ptr = (const int*)d_in[2];
    float*       out   = (float*)d_out;

    const int BSH = in_sizes[0];     // B*S*H
    const int BS  = in_sizes[1];     // B*S
    const int H   = BSH / BS;        // 512
    const int BT  = out_size / H;    // B*T
    const int H4  = H / 4;           // 128 float4 per frame

    int* cum = (int*)d_ws;           // B*S ints = 32 KB scratch

    lr_cumsum_kernel<<<64, 1024, 0, stream>>>(dur, cum, T_ptr, BS, BT);
    lr_expand_kernel<<<BT, 128, 0, stream>>>((const float4*)x, cum, (float4*)out,
                                             T_ptr, BS, BT, H4);
}

// Round 2
// 170.563 us; speedup vs baseline: 1.1136x; 1.1136x over previous
//
#include <hip/hip_runtime.h>
#include <hip/hip_bf16.h>

#define SCAN_BLOCK 512

// Kernel 1: per-row inclusive cumsum of durations (B rows of S).
// B,S derived in-kernel: T = *T_ptr, B = BT/T, S = BS/B.
__global__ __launch_bounds__(SCAN_BLOCK)
void lr_cumsum_kernel(const int* __restrict__ dur, int* __restrict__ cum,
                      const int* __restrict__ T_ptr, int BS, int BT) {
    const int T = *T_ptr;
    const int B = BT / T;
    const int S = BS / B;
    __shared__ int sdata[SCAN_BLOCK];
    const int tid = threadIdx.x;
    for (int row = blockIdx.x; row < B; row += gridDim.x) {
        int carry = 0;
        for (int base = 0; base < S; base += SCAN_BLOCK) {
            const int n = min(SCAN_BLOCK, S - base);
            __syncthreads();
            int v = (tid < n) ? dur[row * S + base + tid] : 0;
            sdata[tid] = v;
            __syncthreads();
            #pragma unroll
            for (int off = 1; off < SCAN_BLOCK; off <<= 1) {
                int add = (tid >= off) ? sdata[tid - off] : 0;
                __syncthreads();
                sdata[tid] += add;
                __syncthreads();
            }
            if (tid < n) cum[row * S + base + tid] = sdata[tid] + carry;
            carry += sdata[SCAN_BLOCK - 1];  // padded slots are 0 -> holds chunk total
        }
    }
}

// Kernel 2: SCATTER. One block per token (b,j). Read the 2KB x-row once into
// registers, stream it to frames [cum[j-1], cum[j]) (clamped to T). No
// dependent-load chains: 2 scalar index loads + 1 coalesced row read.
__global__ __launch_bounds__(128)
void lr_scatter_kernel(const float4* __restrict__ x, const int* __restrict__ cum,
                       float4* __restrict__ out, const int* __restrict__ T_ptr,
                       int BS, int BT, int H4) {
    const int T = *T_ptr;
    const int B = BT / T;
    const int S = BS / B;
    const int id = blockIdx.x;          // flat token index = b*S + j
    const int b  = id / S;
    const int j  = id - b * S;

    int end   = cum[id];
    int start = (j == 0) ? 0 : cum[id - 1];
    end   = min(end, T);
    start = min(start, T);
    if (start >= end) return;           // duration 0 (or fully past T)

    const float4 v = x[(size_t)id * H4 + threadIdx.x];   // row held in registers
    float4* __restrict__ dst = out + ((size_t)b * T + start) * H4 + threadIdx.x;
    for (int f = start; f < end; ++f) {
        *dst = v;
        dst += H4;
    }
}

// Kernel 3: zero the tail frames t >= total[b] (reference zeros frames past the
// expanded length). Predicated streaming store; most threads store nothing.
__global__ __launch_bounds__(256)
void lr_zerotail_kernel(const int* __restrict__ cum, float4* __restrict__ out,
                        const int* __restrict__ T_ptr, int BS, int BT, int H4) {
    const int T = *T_ptr;
    const int B = BT / T;
    const int S = BS / B;
    const long long g = (long long)blockIdx.x * blockDim.x + threadIdx.x;  // float4 idx
    const long long frame = g / H4;      // = b*T + t
    if (frame >= (long long)BT) return;
    const int b = (int)(frame / T);
    const int t = (int)(frame - (long long)b * T);
    const int total = min(cum[b * S + S - 1], T);   // wave-uniform load (L2 hit)
    if (t >= total) {
        out[g] = make_float4(0.f, 0.f, 0.f, 0.f);
    }
}

extern "C" void kernel_launch(void* const* d_in, const int* in_sizes, int n_in,
                              void* d_out, int out_size, void* d_ws, size_t ws_size,
                              hipStream_t stream) {
    const float* x     = (const float*)d_in[0];
    const int*   dur   = (const int*)d_in[1];
    const int*   T_ptr = (const int*)d_in[2];
    float*       out   = (float*)d_out;

    const int BSH = in_sizes[0];     // B*S*H
    const int BS  = in_sizes[1];     // B*S
    const int H   = BSH / BS;        // 512
    const int BT  = out_size / H;    // B*T
    const int H4  = H / 4;           // float4 per frame

    int* cum = (int*)d_ws;           // B*S ints

    lr_cumsum_kernel<<<64, SCAN_BLOCK, 0, stream>>>(dur, cum, T_ptr, BS, BT);
    lr_scatter_kernel<<<BS, 128, 0, stream>>>((const float4*)x, cum, (float4*)out,
                                              T_ptr, BS, BT, H4);
    const long long n4 = (long long)out_size / 4;
    const int zgrid = (int)((n4 + 255) / 256);
    lr_zerotail_kernel<<<zgrid, 256, 0, stream>>>(cum, (float4*)out, T_ptr, BS, BT, H4);
}

// Round 3
// 170.441 us; speedup vs baseline: 1.1144x; 1.0007x over previous
//
#include <hip/hip_runtime.h>
#include <hip/hip_bf16.h>

#define SCAN_BLOCK 512

typedef __attribute__((ext_vector_type(4))) float f32x4;

// Kernel A: per-row inclusive cumsum of durations + frame->token map build.
// map[b*T + t] = flat token id (b*S + j) whose span covers frame t; -1 for tail.
// B,S derived in-kernel: T = *T_ptr, B = BT/T, S = BS/B. Grid-strided over rows.
__global__ __launch_bounds__(SCAN_BLOCK)
void lr_buildmap_kernel(const int* __restrict__ dur, int* __restrict__ map,
                        const int* __restrict__ T_ptr, int BS, int BT) {
    const int T = *T_ptr;
    const int B = BT / T;
    const int S = BS / B;
    __shared__ int sdata[SCAN_BLOCK];
    const int tid = threadIdx.x;
    for (int row = blockIdx.x; row < B; row += gridDim.x) {
        int carry = 0;
        for (int base = 0; base < S; base += SCAN_BLOCK) {
            const int n = min(SCAN_BLOCK, S - base);
            __syncthreads();  // protect sdata reuse across chunks/rows
            const int v = (tid < n) ? dur[row * S + base + tid] : 0;
            sdata[tid] = v;
            __syncthreads();
            #pragma unroll
            for (int off = 1; off < SCAN_BLOCK; off <<= 1) {
                int add = (tid >= off) ? sdata[tid - off] : 0;
                __syncthreads();
                sdata[tid] += add;
                __syncthreads();
            }
            if (tid < n) {
                const int inc   = sdata[tid] + carry;          // inclusive cumsum
                const int end   = min(inc, T);
                const int start = min(inc - v, T);             // exclusive start
                const int tok   = row * S + base + tid;        // flat token id
                for (int t = start; t < end; ++t) map[row * T + t] = tok;
            }
            carry += sdata[SCAN_BLOCK - 1];  // padded slots are 0 -> chunk total
        }
        __syncthreads();
        const int total = min(carry, T);
        for (int t = total + tid; t < T; t += SCAN_BLOCK) map[row * T + t] = -1;
    }
}

// Kernel B: one thread per output float4. frame = g >> shift (no divisions).
// map load is wave-uniform-per-frame (L2 broadcast); x row loads hit L2/L3
// (x is only 16.8 MB); out stores are nontemporal streaming.
__global__ __launch_bounds__(256)
void lr_expand_kernel(const f32x4* __restrict__ x, const int* __restrict__ map,
                      f32x4* __restrict__ out, int n4, int shift) {
    const int g = blockIdx.x * blockDim.x + threadIdx.x;   // < BT*H4 (8.4M) fits int
    if (g >= n4) return;
    const int frame = g >> shift;
    const int lane  = g & ((1 << shift) - 1);
    const int tok   = map[frame];
    f32x4 v = (f32x4)(0.f, 0.f, 0.f, 0.f);
    if (tok >= 0) v = x[((size_t)tok << shift) + lane];
    __builtin_nontemporal_store(v, &out[g]);
}

extern "C" void kernel_launch(void* const* d_in, const int* in_sizes, int n_in,
                              void* d_out, int out_size, void* d_ws, size_t ws_size,
                              hipStream_t stream) {
    const float* x     = (const float*)d_in[0];
    const int*   dur   = (const int*)d_in[1];
    const int*   T_ptr = (const int*)d_in[2];

    const int BSH = in_sizes[0];     // B*S*H
    const int BS  = in_sizes[1];     // B*S
    const int H   = BSH / BS;        // 512
    const int BT  = out_size / H;    // B*T
    const int H4  = H / 4;           // 128 float4 per frame (power of 2)
    const int shift = __builtin_ctz(H4);   // 7

    int* map = (int*)d_ws;           // BT ints = 256 KB scratch

    lr_buildmap_kernel<<<64, SCAN_BLOCK, 0, stream>>>(dur, map, T_ptr, BS, BT);

    const int n4 = out_size / 4;     // BT * H4
    const int grid = (n4 + 255) / 256;
    lr_expand_kernel<<<grid, 256, 0, stream>>>((const f32x4*)x, map, (f32x4*)d_out,
                                               n4, shift);
}